// Round 1
// baseline (918.622 us; speedup 1.0000x reference)
//
#include <hip/hip_runtime.h>

#define B_ 2
#define S_ 2048
#define HID_ 768
#define NH_ 12
#define HD_ 64

typedef unsigned short u16;
typedef __attribute__((ext_vector_type(8))) short bf16x8;
typedef __attribute__((ext_vector_type(4))) float f32x4;

static __device__ inline u16 f2bf(float f) {
    union { float f; unsigned u; } v; v.f = f;
    unsigned r = v.u + 0x7fffu + ((v.u >> 16) & 1u);
    return (u16)(r >> 16);
}

// ---------------- cast fp32 -> bf16, 4 elems/thread ----------------
__global__ void cast_bf16(const float* __restrict__ src, u16* __restrict__ dst, int n) {
    int i = (blockIdx.x * blockDim.x + threadIdx.x) * 4;
    if (i < n) {
        float4 v = *(const float4*)(src + i);
        unsigned lo = (unsigned)f2bf(v.x) | ((unsigned)f2bf(v.y) << 16);
        unsigned hi = (unsigned)f2bf(v.z) | ((unsigned)f2bf(v.w) << 16);
        uint2 o; o.x = lo; o.y = hi;
        *(uint2*)(dst + i) = o;
    }
}

// ---------------- QKV projection GEMM ----------------
// out[m][n] = sum_k hs[m][k] * Wcat[n][k]  (+bias), M=4096, N=2304, K=768
// 64x64 tile per block, 4 waves, each wave 16 rows x 64 cols.
__global__ __launch_bounds__(256) void qkv_gemm(
    const u16* __restrict__ hsb, const u16* __restrict__ wcat,
    const float* __restrict__ bq, const float* __restrict__ bk, const float* __restrict__ bv,
    u16* __restrict__ Qg, u16* __restrict__ Kg, u16* __restrict__ Vtg)
{
    __shared__ u16 As[64 * 40];
    __shared__ u16 Bs[64 * 40];
    __shared__ u16 Vs[64 * 72];

    const int m0 = blockIdx.x * 64;
    const int n0 = blockIdx.y * 64;
    const int tid = threadIdx.x;
    const int wave = tid >> 6, lane = tid & 63;
    const int l = lane & 15, quad = lane >> 4;

    f32x4 acc[4];
#pragma unroll
    for (int t = 0; t < 4; t++) acc[t] = (f32x4){0.f, 0.f, 0.f, 0.f};

    const int srow = tid >> 2;          // 0..63
    const int skg = (tid & 3) * 8;      // 0,8,16,24

    for (int k0 = 0; k0 < HID_; k0 += 32) {
        *(int4*)(&As[srow * 40 + skg]) = *(const int4*)(&hsb[(size_t)(m0 + srow) * HID_ + k0 + skg]);
        *(int4*)(&Bs[srow * 40 + skg]) = *(const int4*)(&wcat[(size_t)(n0 + srow) * HID_ + k0 + skg]);
        __syncthreads();
        bf16x8 a = *(const bf16x8*)(&As[(wave * 16 + l) * 40 + quad * 8]);
#pragma unroll
        for (int t = 0; t < 4; t++) {
            bf16x8 b = *(const bf16x8*)(&Bs[(t * 16 + l) * 40 + quad * 8]);
            acc[t] = __builtin_amdgcn_mfma_f32_16x16x32_bf16(a, b, acc[t], 0, 0, 0);
        }
        __syncthreads();
    }

    // epilogue: whole block is one (proj, head)
    const int proj = n0 / HID_;             // 0=Q 1=K 2=V
    const int cbase = n0 - proj * HID_;     // multiple of 64
    const int h = cbase >> 6;
    const int bidx = m0 >> 11;
    const int srow0 = m0 & (S_ - 1);
    const float* bias = (proj == 0) ? bq : ((proj == 1) ? bk : bv);

    if (proj < 2) {
        u16* dst = (proj == 0) ? Qg : Kg;
        const float sc = (proj == 0) ? 0.125f : 1.0f;
#pragma unroll
        for (int t = 0; t < 4; t++) {
            const int d = t * 16 + l;
            const float bb = bias[cbase + d];
#pragma unroll
            for (int rr = 0; rr < 4; rr++) {
                int s = srow0 + wave * 16 + quad * 4 + rr;
                float v = (acc[t][rr] + bb) * sc;
                dst[(((size_t)bidx * NH_ + h) * S_ + s) * HD_ + d] = f2bf(v);
            }
        }
    } else {
        // V: transpose through LDS, write Vt[b][h][d][s] coalesced
#pragma unroll
        for (int t = 0; t < 4; t++) {
            const int d = t * 16 + l;
            const float bb = bias[cbase + d];
#pragma unroll
            for (int rr = 0; rr < 4; rr++) {
                int sl = wave * 16 + quad * 4 + rr;
                Vs[d * 72 + sl] = f2bf(acc[t][rr] + bb);
            }
        }
        __syncthreads();
        const int drow = tid >> 2;           // d 0..63
        const int sseg = (tid & 3) * 16;     // s segment
        size_t base = (((size_t)bidx * NH_ + h) * HD_ + drow) * S_ + srow0 + sseg;
        *(int4*)(&Vtg[base])     = *(const int4*)(&Vs[drow * 72 + sseg]);
        *(int4*)(&Vtg[base + 8]) = *(const int4*)(&Vs[drow * 72 + sseg + 8]);
    }
}

// ---------------- fused flash attention (swapped QK^T + rel prefetch) ----------------
// grid: (S/64, NH, B), 256 threads = 4 waves, each wave owns 16 q-rows.
// Score MFMA computes S^T = mfma(K, Q): lane holds 4 CONSECUTIVE key cols of one
// q-row -> rel/rel2/mask loads are float4/int4 (12 vector loads per tile instead
// of 48 scalar). These loads are prefetched one k-tile ahead into registers so
// HBM latency hides under the previous tile's MFMA/softmax/PV.
__global__ __launch_bounds__(256) void attn(
    const u16* __restrict__ Qg, const u16* __restrict__ Kg, const u16* __restrict__ Vtg,
    const float* __restrict__ rel, const float* __restrict__ rel2,
    const int* __restrict__ mask, float* __restrict__ out)
{
    __shared__ u16 Ks[64 * 72];
    __shared__ u16 Vts[64 * 72];
    __shared__ u16 Ps[4 * 16 * 72];

    const int q0 = blockIdx.x * 64;
    const int h = blockIdx.y;
    const int b = blockIdx.z;
    const int tid = threadIdx.x;
    const int wave = tid >> 6, lane = tid & 63;
    const int l = lane & 15, quad = lane >> 4;
    const int bh = b * NH_ + h;

    const float NEG = -3.4028234663852886e38f;

    // Q fragments stay in registers for the whole kernel (B-operand of swapped MFMA)
    bf16x8 qf[2];
    {
        const int qrow = q0 + wave * 16 + l;
        qf[0] = *(const bf16x8*)(&Qg[((size_t)bh * S_ + qrow) * HD_ + quad * 8]);
        qf[1] = *(const bf16x8*)(&Qg[((size_t)bh * S_ + qrow) * HD_ + 32 + quad * 8]);
    }

    f32x4 o[4];
#pragma unroll
    for (int t = 0; t < 4; t++) o[t] = (f32x4){0.f, 0.f, 0.f, 0.f};
    float m_run = NEG, l_run = 0.f;   // per-lane: the q-row this lane reduces is q0+wave*16+l

    const int srow = tid >> 2;        // 0..63
    const int sseg = (tid & 3) * 8;   // 0,8,16,24

    // row pointers for this lane's q-row
    const int qrow = q0 + wave * 16 + l;
    const float* relR  = rel  + (size_t)bh * S_ * S_ + (size_t)qrow * S_;
    const float* rel2R = rel2 + (size_t)bh * S_ * S_ + (size_t)qrow * S_;
    const int*   maskR = mask + (size_t)b * S_ * S_ + (size_t)qrow * S_;

    // prefetch tile 0: rel/rel2/mask, 4 consecutive cols per (t) at quad*4
    float4 pr1[4], pr2[4];
    int4 pmk[4];
#pragma unroll
    for (int t = 0; t < 4; t++) {
        const int c = t * 16 + quad * 4;
        pr1[t] = *(const float4*)(relR + c);
        pr2[t] = *(const float4*)(rel2R + c);
        pmk[t] = *(const int4*)(maskR + c);
    }

    for (int k0 = 0; k0 < S_; k0 += 64) {
        // A: issue K/V staging loads into register temps (oldest in vmem queue)
        size_t kg = ((size_t)bh * S_ + k0 + srow) * HD_;
        int4 ka = *(const int4*)(&Kg[kg + sseg]);
        int4 kb = *(const int4*)(&Kg[kg + 32 + sseg]);
        size_t vg = ((size_t)bh * HD_ + srow) * S_ + k0;
        int4 va = *(const int4*)(&Vtg[vg + sseg]);
        int4 vb = *(const int4*)(&Vtg[vg + 32 + sseg]);

        // B: consume prefetched rel/rel2/mask -> score accumulator init.
        // Mask folded pre-MFMA: adding |qk| <= 1e4 to -3.4e38 is absorbed below
        // the ulp, so masked scores are bit-identical to post-MFMA masking.
        f32x4 sacc[4];
#pragma unroll
        for (int t = 0; t < 4; t++) {
            sacc[t][0] = pmk[t].x ? NEG : pr1[t].x + pr2[t].x;
            sacc[t][1] = pmk[t].y ? NEG : pr1[t].y + pr2[t].y;
            sacc[t][2] = pmk[t].z ? NEG : pr1[t].z + pr2[t].z;
            sacc[t][3] = pmk[t].w ? NEG : pr1[t].w + pr2[t].w;
        }

        // C: prefetch next tile's rel/rel2/mask (latency hides under this tile)
        if (k0 + 64 < S_) {
#pragma unroll
            for (int t = 0; t < 4; t++) {
                const int c = k0 + 64 + t * 16 + quad * 4;
                pr1[t] = *(const float4*)(relR + c);
                pr2[t] = *(const float4*)(rel2R + c);
                pmk[t] = *(const int4*)(maskR + c);
            }
        }

        // D: write staged K/V to LDS
        *(int4*)(&Ks[srow * 72 + sseg])       = ka;
        *(int4*)(&Ks[srow * 72 + 32 + sseg])  = kb;
        *(int4*)(&Vts[srow * 72 + sseg])      = va;
        *(int4*)(&Vts[srow * 72 + 32 + sseg]) = vb;
        __syncthreads();

        // E: swapped QK^T: sacc[t][rr] = scores[q=qrow][k = k0 + t*16 + quad*4 + rr]
#pragma unroll
        for (int t = 0; t < 4; t++) {
            bf16x8 b0 = *(const bf16x8*)(&Ks[(t * 16 + l) * 72 + quad * 8]);
            sacc[t] = __builtin_amdgcn_mfma_f32_16x16x32_bf16(b0, qf[0], sacc[t], 0, 0, 0);
            bf16x8 b1 = *(const bf16x8*)(&Ks[(t * 16 + l) * 72 + 32 + quad * 8]);
            sacc[t] = __builtin_amdgcn_mfma_f32_16x16x32_bf16(b1, qf[1], sacc[t], 0, 0, 0);
        }

        // F: online softmax. Lane owns q-row (l); its 16 k-values live in sacc.
        // Lanes {l, l+16, l+32, l+48} share the row -> reduce via xor 16, 32.
        float mx = NEG;
#pragma unroll
        for (int t = 0; t < 4; t++)
#pragma unroll
            for (int rr = 0; rr < 4; rr++) mx = fmaxf(mx, sacc[t][rr]);
        mx = fmaxf(mx, __shfl_xor(mx, 16, 64));
        mx = fmaxf(mx, __shfl_xor(mx, 32, 64));
        float mnew = fmaxf(m_run, mx);
        float alpha = __expf(m_run - mnew);
        float rs = 0.f;
#pragma unroll
        for (int t = 0; t < 4; t++)
#pragma unroll
            for (int rr = 0; rr < 4; rr++) {
                float p = __expf(sacc[t][rr] - mnew);
                sacc[t][rr] = p;
                rs += p;
            }
        rs += __shfl_xor(rs, 16, 64);
        rs += __shfl_xor(rs, 32, 64);
        l_run = l_run * alpha + rs;
        m_run = mnew;

        // redistribute alpha to the PV accumulator layout (o row = quad*4+rr)
        float av[4];
#pragma unroll
        for (int rr = 0; rr < 4; rr++) av[rr] = __shfl(alpha, quad * 4 + rr, 64);
#pragma unroll
        for (int dt = 0; dt < 4; dt++)
#pragma unroll
            for (int rr = 0; rr < 4; rr++) o[dt][rr] *= av[rr];

        // G: write P to LDS [q][k]; lane's 4 values per t are k-consecutive -> uint2
#pragma unroll
        for (int t = 0; t < 4; t++) {
            unsigned p01 = (unsigned)f2bf(sacc[t][0]) | ((unsigned)f2bf(sacc[t][1]) << 16);
            unsigned p23 = (unsigned)f2bf(sacc[t][2]) | ((unsigned)f2bf(sacc[t][3]) << 16);
            uint2 pw; pw.x = p01; pw.y = p23;
            *(uint2*)(&Ps[(wave * 16 + l) * 72 + t * 16 + quad * 4]) = pw;
        }
        __syncthreads();

        // H: PV: O += P * V
        bf16x8 pa0 = *(const bf16x8*)(&Ps[(wave * 16 + l) * 72 + quad * 8]);
        bf16x8 pa1 = *(const bf16x8*)(&Ps[(wave * 16 + l) * 72 + 32 + quad * 8]);
#pragma unroll
        for (int dt = 0; dt < 4; dt++) {
            bf16x8 v0 = *(const bf16x8*)(&Vts[(dt * 16 + l) * 72 + quad * 8]);
            o[dt] = __builtin_amdgcn_mfma_f32_16x16x32_bf16(pa0, v0, o[dt], 0, 0, 0);
            bf16x8 v1 = *(const bf16x8*)(&Vts[(dt * 16 + l) * 72 + 32 + quad * 8]);
            o[dt] = __builtin_amdgcn_mfma_f32_16x16x32_bf16(pa1, v1, o[dt], 0, 0, 0);
        }
        __syncthreads();
    }

    // epilogue: out[b][s][h*64+d] = O / l_run(q).  l_run lives on lane q (0..15);
    // o row index is quad*4+rr -> gather via shuffle.
    float lv[4];
#pragma unroll
    for (int rr = 0; rr < 4; rr++) lv[rr] = __shfl(l_run, quad * 4 + rr, 64);
#pragma unroll
    for (int dt = 0; dt < 4; dt++) {
#pragma unroll
        for (int rr = 0; rr < 4; rr++) {
            const int row = q0 + wave * 16 + quad * 4 + rr;
            out[((size_t)b * S_ + row) * HID_ + h * HD_ + dt * 16 + l] = o[dt][rr] / lv[rr];
        }
    }
}

extern "C" void kernel_launch(void* const* d_in, const int* in_sizes, int n_in,
                              void* d_out, int out_size, void* d_ws, size_t ws_size,
                              hipStream_t stream) {
    const float* hs   = (const float*)d_in[0];
    const float* rel  = (const float*)d_in[1];
    const float* rel2 = (const float*)d_in[2];
    const int*   mask = (const int*)d_in[3];
    const float* Wq = (const float*)d_in[4];
    const float* bq = (const float*)d_in[5];
    const float* Wk = (const float*)d_in[6];
    const float* bk = (const float*)d_in[7];
    const float* Wv = (const float*)d_in[8];
    const float* bv = (const float*)d_in[9];
    float* out = (float*)d_out;

    char* ws = (char*)d_ws;
    u16* hsb  = (u16*)(ws);                      // 4096*768   bf16 = 6291456 B
    u16* wcat = (u16*)(ws + 6291456);            // 2304*768   bf16 = 3538944 B
    u16* Qg   = (u16*)(ws + 9830400);            // [B][NH][S][HD] bf16 = 6291456 B
    u16* Kg   = (u16*)(ws + 16121856);           // same
    u16* Vtg  = (u16*)(ws + 22413312);           // [B][NH][HD][S] bf16

    // casts
    cast_bf16<<<3072, 256, 0, stream>>>(hs, hsb, B_ * S_ * HID_);
    cast_bf16<<<576, 256, 0, stream>>>(Wq, wcat,             HID_ * HID_);
    cast_bf16<<<576, 256, 0, stream>>>(Wk, wcat + HID_ * HID_,     HID_ * HID_);
    cast_bf16<<<576, 256, 0, stream>>>(Wv, wcat + 2 * HID_ * HID_, HID_ * HID_);

    // QKV projections
    qkv_gemm<<<dim3(64, 36), 256, 0, stream>>>(hsb, wcat, bq, bk, bv, Qg, Kg, Vtg);

    // fused attention
    attn<<<dim3(S_ / 64, NH_, B_), 256, 0, stream>>>(Qg, Kg, Vtg, rel, rel2, mask, out);
}

// Round 2
// 900.004 us; speedup vs baseline: 1.0207x; 1.0207x over previous
//
#include <hip/hip_runtime.h>

#define B_ 2
#define S_ 2048
#define HID_ 768
#define NH_ 12
#define HD_ 64

typedef unsigned short u16;
typedef __attribute__((ext_vector_type(8))) short bf16x8;
typedef __attribute__((ext_vector_type(4))) float f32x4;

static __device__ inline u16 f2bf(float f) {
    union { float f; unsigned u; } v; v.f = f;
    unsigned r = v.u + 0x7fffu + ((v.u >> 16) & 1u);
    return (u16)(r >> 16);
}

// LDS-only barrier: waits ds ops, leaves vmcnt (global loads) IN FLIGHT.
// __syncthreads() would emit s_waitcnt vmcnt(0) and drain our prefetch.
#define LDS_BARRIER() asm volatile("s_waitcnt lgkmcnt(0)\n\ts_barrier" ::: "memory")

// ---------------- cast fp32 -> bf16, 4 elems/thread ----------------
__global__ void cast_bf16(const float* __restrict__ src, u16* __restrict__ dst, int n) {
    int i = (blockIdx.x * blockDim.x + threadIdx.x) * 4;
    if (i < n) {
        float4 v = *(const float4*)(src + i);
        unsigned lo = (unsigned)f2bf(v.x) | ((unsigned)f2bf(v.y) << 16);
        unsigned hi = (unsigned)f2bf(v.z) | ((unsigned)f2bf(v.w) << 16);
        uint2 o; o.x = lo; o.y = hi;
        *(uint2*)(dst + i) = o;
    }
}

// ---------------- QKV projection GEMM ----------------
// out[m][n] = sum_k hs[m][k] * Wcat[n][k]  (+bias), M=4096, N=2304, K=768
// 64x64 tile per block, 4 waves, each wave 16 rows x 64 cols.
__global__ __launch_bounds__(256) void qkv_gemm(
    const u16* __restrict__ hsb, const u16* __restrict__ wcat,
    const float* __restrict__ bq, const float* __restrict__ bk, const float* __restrict__ bv,
    u16* __restrict__ Qg, u16* __restrict__ Kg, u16* __restrict__ Vtg)
{
    __shared__ u16 As[64 * 40];
    __shared__ u16 Bs[64 * 40];
    __shared__ u16 Vs[64 * 72];

    const int m0 = blockIdx.x * 64;
    const int n0 = blockIdx.y * 64;
    const int tid = threadIdx.x;
    const int wave = tid >> 6, lane = tid & 63;
    const int l = lane & 15, quad = lane >> 4;

    f32x4 acc[4];
#pragma unroll
    for (int t = 0; t < 4; t++) acc[t] = (f32x4){0.f, 0.f, 0.f, 0.f};

    const int srow = tid >> 2;          // 0..63
    const int skg = (tid & 3) * 8;      // 0,8,16,24

    for (int k0 = 0; k0 < HID_; k0 += 32) {
        *(int4*)(&As[srow * 40 + skg]) = *(const int4*)(&hsb[(size_t)(m0 + srow) * HID_ + k0 + skg]);
        *(int4*)(&Bs[srow * 40 + skg]) = *(const int4*)(&wcat[(size_t)(n0 + srow) * HID_ + k0 + skg]);
        __syncthreads();
        bf16x8 a = *(const bf16x8*)(&As[(wave * 16 + l) * 40 + quad * 8]);
#pragma unroll
        for (int t = 0; t < 4; t++) {
            bf16x8 b = *(const bf16x8*)(&Bs[(t * 16 + l) * 40 + quad * 8]);
            acc[t] = __builtin_amdgcn_mfma_f32_16x16x32_bf16(a, b, acc[t], 0, 0, 0);
        }
        __syncthreads();
    }

    // epilogue: whole block is one (proj, head)
    const int proj = n0 / HID_;             // 0=Q 1=K 2=V
    const int cbase = n0 - proj * HID_;     // multiple of 64
    const int h = cbase >> 6;
    const int bidx = m0 >> 11;
    const int srow0 = m0 & (S_ - 1);
    const float* bias = (proj == 0) ? bq : ((proj == 1) ? bk : bv);

    if (proj < 2) {
        u16* dst = (proj == 0) ? Qg : Kg;
        const float sc = (proj == 0) ? 0.125f : 1.0f;
#pragma unroll
        for (int t = 0; t < 4; t++) {
            const int d = t * 16 + l;
            const float bb = bias[cbase + d];
#pragma unroll
            for (int rr = 0; rr < 4; rr++) {
                int s = srow0 + wave * 16 + quad * 4 + rr;
                float v = (acc[t][rr] + bb) * sc;
                dst[(((size_t)bidx * NH_ + h) * S_ + s) * HD_ + d] = f2bf(v);
            }
        }
    } else {
        // V: transpose through LDS, write Vt[b][h][d][s] coalesced
#pragma unroll
        for (int t = 0; t < 4; t++) {
            const int d = t * 16 + l;
            const float bb = bias[cbase + d];
#pragma unroll
            for (int rr = 0; rr < 4; rr++) {
                int sl = wave * 16 + quad * 4 + rr;
                Vs[d * 72 + sl] = f2bf(acc[t][rr] + bb);
            }
        }
        __syncthreads();
        const int drow = tid >> 2;           // d 0..63
        const int sseg = (tid & 3) * 16;     // s segment
        size_t base = (((size_t)bidx * NH_ + h) * HD_ + drow) * S_ + srow0 + sseg;
        *(int4*)(&Vtg[base])     = *(const int4*)(&Vs[drow * 72 + sseg]);
        *(int4*)(&Vtg[base + 8]) = *(const int4*)(&Vs[drow * 72 + sseg + 8]);
    }
}

// ---------------- fused flash attention ----------------
// grid: (S/64, NH, B), 256 threads = 4 waves, each wave owns 16 q-rows.
// Swapped QK^T (mfma(K,Q) -> S^T): lane holds 4 CONSECUTIVE key cols of one
// q-row, so rel/rel2/mask are float4/int4 loads, prefetched one k-tile ahead.
// Barriers are LDS-only (lgkmcnt), so the prefetch stays in flight across the
// whole MFMA+softmax+PV phase instead of being drained by __syncthreads.
__global__ __launch_bounds__(256) void attn(
    const u16* __restrict__ Qg, const u16* __restrict__ Kg, const u16* __restrict__ Vtg,
    const float* __restrict__ rel, const float* __restrict__ rel2,
    const int* __restrict__ mask, float* __restrict__ out)
{
    __shared__ u16 Ks[64 * 72];
    __shared__ u16 Vts[64 * 72];
    __shared__ u16 Ps[4 * 16 * 72];

    const int q0 = blockIdx.x * 64;
    const int h = blockIdx.y;
    const int b = blockIdx.z;
    const int tid = threadIdx.x;
    const int wave = tid >> 6, lane = tid & 63;
    const int l = lane & 15, quad = lane >> 4;
    const int bh = b * NH_ + h;

    const float NEG = -3.4028234663852886e38f;

    // Q fragments stay in registers for the whole kernel (B-operand of swapped MFMA)
    bf16x8 qf[2];
    {
        const int qr = q0 + wave * 16 + l;
        qf[0] = *(const bf16x8*)(&Qg[((size_t)bh * S_ + qr) * HD_ + quad * 8]);
        qf[1] = *(const bf16x8*)(&Qg[((size_t)bh * S_ + qr) * HD_ + 32 + quad * 8]);
    }

    f32x4 o[4];
#pragma unroll
    for (int t = 0; t < 4; t++) o[t] = (f32x4){0.f, 0.f, 0.f, 0.f};
    float m_run = NEG, l_run = 0.f;   // per-lane: this lane reduces q-row q0+wave*16+l

    const int srow = tid >> 2;        // 0..63
    const int sseg = (tid & 3) * 8;   // 0,8,16,24

    // row pointers for this lane's q-row
    const int qrow = q0 + wave * 16 + l;
    const float* relR  = rel  + (size_t)bh * S_ * S_ + (size_t)qrow * S_;
    const float* rel2R = rel2 + (size_t)bh * S_ * S_ + (size_t)qrow * S_;
    const int*   maskR = mask + (size_t)b * S_ * S_ + (size_t)qrow * S_;

    // prefetch tile 0: rel/rel2/mask, 4 consecutive cols per (t) at quad*4
    float4 pr1[4], pr2[4];
    int4 pmk[4];
#pragma unroll
    for (int t = 0; t < 4; t++) {
        const int c = t * 16 + quad * 4;
        pr1[t] = *(const float4*)(relR + c);
        pr2[t] = *(const float4*)(rel2R + c);
        pmk[t] = *(const int4*)(maskR + c);
    }

    for (int k0 = 0; k0 < S_; k0 += 64) {
        // A: issue K/V staging loads into register temps (oldest in vmem queue)
        size_t kg = ((size_t)bh * S_ + k0 + srow) * HD_;
        int4 ka = *(const int4*)(&Kg[kg + sseg]);
        int4 kb = *(const int4*)(&Kg[kg + 32 + sseg]);
        size_t vg = ((size_t)bh * HD_ + srow) * S_ + k0;
        int4 va = *(const int4*)(&Vtg[vg + sseg]);
        int4 vb = *(const int4*)(&Vtg[vg + 32 + sseg]);

        // B: consume prefetched rel/rel2/mask -> score accumulator init.
        // Mask folded pre-MFMA: adding |qk| <= 1e4 to -3.4e38 is absorbed below
        // the ulp, so masked scores are bit-identical to post-MFMA masking.
        f32x4 sacc[4];
#pragma unroll
        for (int t = 0; t < 4; t++) {
            sacc[t][0] = pmk[t].x ? NEG : pr1[t].x + pr2[t].x;
            sacc[t][1] = pmk[t].y ? NEG : pr1[t].y + pr2[t].y;
            sacc[t][2] = pmk[t].z ? NEG : pr1[t].z + pr2[t].z;
            sacc[t][3] = pmk[t].w ? NEG : pr1[t].w + pr2[t].w;
        }

        // C: prefetch next tile's rel/rel2/mask. These stay in flight across the
        // LDS-only barrier below and complete under this tile's MFMA/softmax/PV.
        if (k0 + 64 < S_) {
#pragma unroll
            for (int t = 0; t < 4; t++) {
                const int c = k0 + 64 + t * 16 + quad * 4;
                pr1[t] = *(const float4*)(relR + c);
                pr2[t] = *(const float4*)(rel2R + c);
                pmk[t] = *(const int4*)(maskR + c);
            }
        }

        // D: write staged K/V to LDS (compiler inserts counted vmcnt for ka..vb,
        // leaving the 12 prefetch loads outstanding)
        *(int4*)(&Ks[srow * 72 + sseg])       = ka;
        *(int4*)(&Ks[srow * 72 + 32 + sseg])  = kb;
        *(int4*)(&Vts[srow * 72 + sseg])      = va;
        *(int4*)(&Vts[srow * 72 + 32 + sseg]) = vb;
        LDS_BARRIER();   // staging visible to all waves; vmcnt untouched

        // E: swapped QK^T: sacc[t][rr] = scores[q=qrow][k = k0 + t*16 + quad*4 + rr]
#pragma unroll
        for (int t = 0; t < 4; t++) {
            bf16x8 b0 = *(const bf16x8*)(&Ks[(t * 16 + l) * 72 + quad * 8]);
            sacc[t] = __builtin_amdgcn_mfma_f32_16x16x32_bf16(b0, qf[0], sacc[t], 0, 0, 0);
            bf16x8 b1 = *(const bf16x8*)(&Ks[(t * 16 + l) * 72 + 32 + quad * 8]);
            sacc[t] = __builtin_amdgcn_mfma_f32_16x16x32_bf16(b1, qf[1], sacc[t], 0, 0, 0);
        }

        // F: online softmax. Lane owns q-row (l); lanes {l, l+16, l+32, l+48}
        // share the row -> reduce via xor 16, 32.
        float mx = NEG;
#pragma unroll
        for (int t = 0; t < 4; t++)
#pragma unroll
            for (int rr = 0; rr < 4; rr++) mx = fmaxf(mx, sacc[t][rr]);
        mx = fmaxf(mx, __shfl_xor(mx, 16, 64));
        mx = fmaxf(mx, __shfl_xor(mx, 32, 64));
        float mnew = fmaxf(m_run, mx);
        float alpha = __expf(m_run - mnew);
        float rs = 0.f;
#pragma unroll
        for (int t = 0; t < 4; t++)
#pragma unroll
            for (int rr = 0; rr < 4; rr++) {
                float p = __expf(sacc[t][rr] - mnew);
                sacc[t][rr] = p;
                rs += p;
            }
        rs += __shfl_xor(rs, 16, 64);
        rs += __shfl_xor(rs, 32, 64);
        l_run = l_run * alpha + rs;
        m_run = mnew;

        // redistribute alpha to the PV accumulator layout (o row = quad*4+rr)
        float av[4];
#pragma unroll
        for (int rr = 0; rr < 4; rr++) av[rr] = __shfl(alpha, quad * 4 + rr, 64);
#pragma unroll
        for (int dt = 0; dt < 4; dt++)
#pragma unroll
            for (int rr = 0; rr < 4; rr++) o[dt][rr] *= av[rr];

        // G: write P to LDS [q][k]. P tile rows wave*16..wave*16+15 are
        // WAVE-PRIVATE (written and read only by this wave); same-wave DS ops
        // complete in order, so no barrier is needed between G and H.
#pragma unroll
        for (int t = 0; t < 4; t++) {
            unsigned p01 = (unsigned)f2bf(sacc[t][0]) | ((unsigned)f2bf(sacc[t][1]) << 16);
            unsigned p23 = (unsigned)f2bf(sacc[t][2]) | ((unsigned)f2bf(sacc[t][3]) << 16);
            uint2 pw; pw.x = p01; pw.y = p23;
            *(uint2*)(&Ps[(wave * 16 + l) * 72 + t * 16 + quad * 4]) = pw;
        }

        // H: PV: O += P * V
        bf16x8 pa0 = *(const bf16x8*)(&Ps[(wave * 16 + l) * 72 + quad * 8]);
        bf16x8 pa1 = *(const bf16x8*)(&Ps[(wave * 16 + l) * 72 + 32 + quad * 8]);
#pragma unroll
        for (int dt = 0; dt < 4; dt++) {
            bf16x8 v0 = *(const bf16x8*)(&Vts[(dt * 16 + l) * 72 + quad * 8]);
            o[dt] = __builtin_amdgcn_mfma_f32_16x16x32_bf16(pa0, v0, o[dt], 0, 0, 0);
            bf16x8 v1 = *(const bf16x8*)(&Vts[(dt * 16 + l) * 72 + 32 + quad * 8]);
            o[dt] = __builtin_amdgcn_mfma_f32_16x16x32_bf16(pa1, v1, o[dt], 0, 0, 0);
        }
        LDS_BARRIER();   // all waves' LDS reads done before next tile's staging
    }

    // epilogue: out[b][s][h*64+d] = O / l_run(q).  l_run lives on lane q (0..15);
    // o row index is quad*4+rr -> gather via shuffle.
    float lv[4];
#pragma unroll
    for (int rr = 0; rr < 4; rr++) lv[rr] = __shfl(l_run, quad * 4 + rr, 64);
#pragma unroll
    for (int dt = 0; dt < 4; dt++) {
#pragma unroll
        for (int rr = 0; rr < 4; rr++) {
            const int row = q0 + wave * 16 + quad * 4 + rr;
            out[((size_t)b * S_ + row) * HID_ + h * HD_ + dt * 16 + l] = o[dt][rr] / lv[rr];
        }
    }
}

extern "C" void kernel_launch(void* const* d_in, const int* in_sizes, int n_in,
                              void* d_out, int out_size, void* d_ws, size_t ws_size,
                              hipStream_t stream) {
    const float* hs   = (const float*)d_in[0];
    const float* rel  = (const float*)d_in[1];
    const float* rel2 = (const float*)d_in[2];
    const int*   mask = (const int*)d_in[3];
    const float* Wq = (const float*)d_in[4];
    const float* bq = (const float*)d_in[5];
    const float* Wk = (const float*)d_in[6];
    const float* bk = (const float*)d_in[7];
    const float* Wv = (const float*)d_in[8];
    const float* bv = (const float*)d_in[9];
    float* out = (float*)d_out;

    char* ws = (char*)d_ws;
    u16* hsb  = (u16*)(ws);                      // 4096*768   bf16 = 6291456 B
    u16* wcat = (u16*)(ws + 6291456);            // 2304*768   bf16 = 3538944 B
    u16* Qg   = (u16*)(ws + 9830400);            // [B][NH][S][HD] bf16 = 6291456 B
    u16* Kg   = (u16*)(ws + 16121856);           // same
    u16* Vtg  = (u16*)(ws + 22413312);           // [B][NH][HD][S] bf16

    // casts
    cast_bf16<<<3072, 256, 0, stream>>>(hs, hsb, B_ * S_ * HID_);
    cast_bf16<<<576, 256, 0, stream>>>(Wq, wcat,             HID_ * HID_);
    cast_bf16<<<576, 256, 0, stream>>>(Wk, wcat + HID_ * HID_,     HID_ * HID_);
    cast_bf16<<<576, 256, 0, stream>>>(Wv, wcat + 2 * HID_ * HID_, HID_ * HID_);

    // QKV projections
    qkv_gemm<<<dim3(64, 36), 256, 0, stream>>>(hsb, wcat, bq, bk, bv, Qg, Kg, Vtg);

    // fused attention
    attn<<<dim3(S_ / 64, NH_, B_), 256, 0, stream>>>(Qg, Kg, Vtg, rel, rel2, mask, out);
}